// Round 3
// baseline (2502.490 us; speedup 1.0000x reference)
//
#include <hip/hip_runtime.h>
#include <hip/hip_bf16.h>
#include <cstdint>

// Problem dims (Transformer-XL)
#define QL      512
#define BS      4
#define DMODEL  1024
#define NL      4
#define NH      16
#define DHEAD   64
#define DINNER  4096
#define MLEN    512
#define KLEN_   1024   // MLEN + QL
#define HD_     1024   // NH*DHEAD
#define THD     3072   // 3*HD
#define ROWS_H   2048  // QL*BS

typedef __attribute__((ext_vector_type(8))) __bf16 bf16x8;
typedef __attribute__((ext_vector_type(4))) float  f32x4;

enum EpiMode { EPI_F32 = 0, EPI_BF16 = 1, EPI_RELU_BF16 = 2, EPI_BIAS_F32 = 3, EPI_SHIFT = 4 };

// ======================= MFMA GEMM: C = A(MxK) * Bt(NxK)^T =======================
// A row-major (lda), Bt row-major (ldb) -- both bf16. 256 threads, 4 waves.
// Batch (blockIdx.z = bz): A += bz*sA; Bt += bz*Bn; C offset += bz*Cn.
template<int BM, int BN, int WMT, int WNT, int EPI>
__global__ __launch_bounds__(256) void gemm_bt(
    const __bf16* __restrict__ A, const __bf16* __restrict__ Bt,
    void* __restrict__ Cv, const float* __restrict__ bias,
    int K, int lda, int ldb, int ldc,
    long sA, long Bn, long Cn)
{
  constexpr int WCOLS = BN / (WNT * 16);
  constexpr int WROWS = BM / (WMT * 16);
  static_assert(WCOLS * WROWS == 4, "must be 4 waves");
  constexpr int CHA = BM * 16 + 16;
  constexpr int CHB = BN * 16 + 16;
  __shared__ __align__(16) char smem[4 * CHA + 4 * CHB];
  char* sAm = smem;
  char* sBm = smem + 4 * CHA;

  const int bz = blockIdx.z;
  A  += (size_t)bz * sA;
  Bt += (size_t)bz * Bn;
  const size_t coff = (size_t)bz * Cn;

  const int tid  = threadIdx.x;
  const int wave = tid >> 6, lane = tid & 63;
  const int quad = lane >> 4, mrow = lane & 15;
  const int wr = wave / WCOLS, wc = wave % WCOLS;
  const int bm0 = blockIdx.x * BM, bn0 = blockIdx.y * BN;

  const f32x4 zero = {0.f, 0.f, 0.f, 0.f};
  f32x4 acc[WMT][WNT];
#pragma unroll
  for (int a = 0; a < WMT; ++a)
#pragma unroll
    for (int b = 0; b < WNT; ++b) acc[a][b] = zero;

  for (int k0 = 0; k0 < K; k0 += 32) {
    // stage A tile (BM x 32)
#pragma unroll
    for (int p = 0; p < BM / 64; ++p) {
      int idx = p * 256 + tid;
      int r = idx >> 2, q = idx & 3;
      bf16x8 va = *(const bf16x8*)(A + (size_t)(bm0 + r) * lda + k0 + q * 8);
      *(bf16x8*)(sAm + q * CHA + r * 16) = va;
    }
    // stage B tile (BN x 32)
#pragma unroll
    for (int p = 0; p < BN / 64; ++p) {
      int idx = p * 256 + tid;
      int r = idx >> 2, q = idx & 3;
      bf16x8 vb = *(const bf16x8*)(Bt + (size_t)(bn0 + r) * ldb + k0 + q * 8);
      *(bf16x8*)(sBm + q * CHB + r * 16) = vb;
    }
    __syncthreads();
    bf16x8 afr[WMT], bfr[WNT];
#pragma unroll
    for (int mt = 0; mt < WMT; ++mt)
      afr[mt] = *(const bf16x8*)(sAm + quad * CHA + (wr * (WMT * 16) + mt * 16 + mrow) * 16);
#pragma unroll
    for (int nt = 0; nt < WNT; ++nt)
      bfr[nt] = *(const bf16x8*)(sBm + quad * CHB + (wc * (WNT * 16) + nt * 16 + mrow) * 16);
#pragma unroll
    for (int mt = 0; mt < WMT; ++mt)
#pragma unroll
      for (int nt = 0; nt < WNT; ++nt)
        acc[mt][nt] = __builtin_amdgcn_mfma_f32_16x16x32_bf16(afr[mt], bfr[nt], acc[mt][nt], 0, 0, 0);
    __syncthreads();
  }

  // epilogue: C/D layout col=lane&15, row=quad*4+reg (m89-verified)
#pragma unroll
  for (int mt = 0; mt < WMT; ++mt) {
#pragma unroll
    for (int nt = 0; nt < WNT; ++nt) {
#pragma unroll
      for (int rr = 0; rr < 4; ++rr) {
        int gm = bm0 + wr * (WMT * 16) + mt * 16 + quad * 4 + rr;
        int gn = bn0 + wc * (WNT * 16) + nt * 16 + mrow;
        float val = acc[mt][nt][rr];
        if constexpr (EPI == EPI_F32) {
          ((float*)Cv)[coff + (size_t)gm * ldc + gn] = val;
        } else if constexpr (EPI == EPI_BF16) {
          ((__bf16*)Cv)[coff + (size_t)gm * ldc + gn] = (__bf16)val;
        } else if constexpr (EPI == EPI_RELU_BF16) {
          val += bias[gn];
          ((__bf16*)Cv)[coff + (size_t)gm * ldc + gn] = (__bf16)fmaxf(val, 0.f);
        } else if constexpr (EPI == EPI_BIAS_F32) {
          if (bias) val += bias[gn];
          ((float*)Cv)[coff + (size_t)gm * ldc + gn] = val;
        } else { // EPI_SHIFT: rel_shift scatter-add: raw[i][c] -> score[i][c+i-(QL-1)]
          int j = gn + gm - (QL - 1);
          if (j >= 0) {
            float* cp = (float*)Cv + coff + (size_t)gm * ldc + j;
            *cp += val;
          }
        }
      }
    }
  }
}

// ======================= helpers =======================

// fused fp32->bf16 transpose: out[c][r] = (bf16)in[r][c]; tile 64x64, block (32,8)
__global__ __launch_bounds__(256) void transpose_f32_bf16(
    const float* __restrict__ in, unsigned short* __restrict__ out, int R, int C)
{
  __shared__ float tile[64][66];
  int c0 = blockIdx.x * 64, r0 = blockIdx.y * 64;
  int tx = threadIdx.x, ty = threadIdx.y;  // (32,8)
#pragma unroll
  for (int s = 0; s < 8; ++s) {
    int r = ty + s * 8;
    const float* p = in + (size_t)(r0 + r) * C + c0 + 2 * tx;
    tile[r][2 * tx]     = p[0];
    tile[r][2 * tx + 1] = p[1];
  }
  __syncthreads();
#pragma unroll
  for (int s = 0; s < 8; ++s) {
    int c = ty + s * 8;
    __bf16 lo = (__bf16)tile[2 * tx][c];
    __bf16 hi = (__bf16)tile[2 * tx + 1][c];
    unsigned int w = (unsigned int)*(unsigned short*)&lo |
                     ((unsigned int)*(unsigned short*)&hi << 16);
    *(unsigned int*)(out + (size_t)(c0 + c) * R + r0 + 2 * tx) = w;
  }
}

// fp32 -> bf16 cast
__global__ __launch_bounds__(256) void cast_f32_bf16(const float* __restrict__ in,
                                                     __bf16* __restrict__ out, int n)
{
  int i = blockIdx.x * 256 + threadIdx.x;
  if (i < n) out[i] = (__bf16)in[i];
}

// positional embedding r[p][c], p in [0,KLEN), c in [0,DMODEL); pos = KLEN-1-p
__global__ __launch_bounds__(256) void posemb_kernel(__bf16* __restrict__ r)
{
  int idx = blockIdx.x * 256 + threadIdx.x;        // KLEN_*DMODEL total
  int p = idx >> 10, c = idx & 1023;
  int t = c & 511;
  float invf = __expf(-((float)t / 512.0f) * 9.210340371976184f); // 10000^(-2t/D)
  float ang = (float)(KLEN_ - 1 - p) * invf;
  float val = (c < 512) ? sinf(ang) : cosf(ang);
  r[idx] = (__bf16)val;
}

// h master init from fp32 x: hm (fp32) and hbf (bf16)
__global__ __launch_bounds__(256) void init_h(const float* __restrict__ x,
                                              float* __restrict__ hm,
                                              __bf16* __restrict__ hbf, int n)
{
  int i = blockIdx.x * 256 + threadIdx.x;
  if (i < n) { float t = x[i]; hm[i] = t; hbf[i] = (__bf16)t; }
}

// qu/qv: [bn][i][d] = qh[(MLEN+i)*BS+b][n*64+d] + u/v[n*64+d]   (u,v fp32)
__global__ __launch_bounds__(256) void build_quqv(const __bf16* __restrict__ heads,
                                                  const float* __restrict__ u,
                                                  const float* __restrict__ v,
                                                  __bf16* __restrict__ qu,
                                                  __bf16* __restrict__ qv)
{
  int idx = blockIdx.x * 256 + threadIdx.x;   // BS*NH*QL*DHEAD total
  int d = idx & 63;
  int i = (idx >> 6) & (QL - 1);
  int bn = idx >> 15;
  int b = bn >> 4, n = bn & 15;
  float q = (float)heads[(size_t)((MLEN + i) * BS + b) * THD + n * 64 + d];
  int ud = n * 64 + d;
  qu[idx] = (__bf16)(q + u[ud]);
  qv[idx] = (__bf16)(q + v[ud]);
}

// vt[bn][d][j] = heads[(j*BS+b)*THD + 2048 + n*64 + d]  (transpose via LDS)
__global__ __launch_bounds__(256) void build_vt(const unsigned short* __restrict__ heads,
                                                unsigned short* __restrict__ vt)
{
  __shared__ unsigned short tile[64][65];
  int bn = blockIdx.y; int b = bn >> 4, n = bn & 15;
  int j0 = blockIdx.x * 64;
  int tx = threadIdx.x, ty = threadIdx.y;  // (64,4)
#pragma unroll
  for (int s = 0; s < 16; ++s) {
    int j = ty + s * 4;
    tile[j][tx] = heads[(size_t)((j0 + j) * BS + b) * THD + 2048 + n * 64 + tx];
  }
  __syncthreads();
#pragma unroll
  for (int s = 0; s < 16; ++s) {
    int d = ty + s * 4;
    vt[(size_t)bn * DHEAD * KLEN_ + (size_t)d * KLEN_ + j0 + tx] = tile[tx][d];
  }
}

// masked softmax over k; fp32 score row -> bf16 attn written IN-PLACE into the
// first 2048 bytes of the same row (all reads precede the first barrier).
__global__ __launch_bounds__(256) void softmax_kernel(float* __restrict__ score)
{
  int row = blockIdx.x;
  int i = row & (QL - 1);
  float* s = score + (size_t)row * KLEN_;
  __bf16* a = (__bf16*)s;          // in-place, row stride 2*KLEN_ bf16 elems
  int tid = threadIdx.x;
  int jmax = i + MLEN;
  float v[4]; float mx = -3.0e38f;
#pragma unroll
  for (int p = 0; p < 4; ++p) {
    int j = p * 256 + tid;
    float x = (j <= jmax) ? s[j] * 0.125f : -3.0e38f;
    v[p] = x; mx = fmaxf(mx, x);
  }
#pragma unroll
  for (int off = 32; off > 0; off >>= 1) mx = fmaxf(mx, __shfl_xor(mx, off));
  __shared__ float red[4], red2[4];
  int wave = tid >> 6, lane = tid & 63;
  if (lane == 0) red[wave] = mx;
  __syncthreads();
  mx = fmaxf(fmaxf(red[0], red[1]), fmaxf(red[2], red[3]));
  float sum = 0.f;
#pragma unroll
  for (int p = 0; p < 4; ++p) { v[p] = __expf(v[p] - mx); sum += v[p]; }
#pragma unroll
  for (int off = 32; off > 0; off >>= 1) sum += __shfl_xor(sum, off);
  if (lane == 0) red2[wave] = sum;
  __syncthreads();
  sum = red2[0] + red2[1] + red2[2] + red2[3];
  float inv = 1.0f / sum;
#pragma unroll
  for (int p = 0; p < 4; ++p) {
    int j = p * 256 + tid;
    a[j] = (__bf16)(v[p] * inv);
  }
}

// h = LN(h + delta); writes fp32 master + bf16 shadow (+ optional fp32 out).
__global__ __launch_bounds__(256) void ln_kernel(float* __restrict__ hm,
                                                 const float* __restrict__ delta,
                                                 const float* __restrict__ g,
                                                 const float* __restrict__ b,
                                                 __bf16* __restrict__ hbf,
                                                 float* __restrict__ outf)
{
  int row = blockIdx.x;
  size_t base = (size_t)row * DMODEL;
  int tid = threadIdx.x;
  float x[4]; float sum = 0.f, sq = 0.f;
#pragma unroll
  for (int p = 0; p < 4; ++p) {
    int c = p * 256 + tid;
    float t = hm[base + c] + delta[base + c];
    x[p] = t; sum += t; sq += t * t;
  }
#pragma unroll
  for (int off = 32; off > 0; off >>= 1) { sum += __shfl_xor(sum, off); sq += __shfl_xor(sq, off); }
  __shared__ float rs[4], rq[4];
  int wave = tid >> 6, lane = tid & 63;
  if (lane == 0) { rs[wave] = sum; rq[wave] = sq; }
  __syncthreads();
  sum = rs[0] + rs[1] + rs[2] + rs[3];
  sq  = rq[0] + rq[1] + rq[2] + rq[3];
  float mu  = sum * (1.0f / DMODEL);
  float var = sq * (1.0f / DMODEL) - mu * mu;
  float rstd = rsqrtf(var + 1e-5f);
#pragma unroll
  for (int p = 0; p < 4; ++p) {
    int c = p * 256 + tid;
    float y = (x[p] - mu) * rstd * g[c] + b[c];
    hm[base + c] = y;
    hbf[base + c] = (__bf16)y;
    if (outf) outf[base + c] = y;
  }
}

// ======================= host =======================
extern "C" void kernel_launch(void* const* d_in, const int* in_sizes, int n_in,
                              void* d_out, int out_size, void* d_ws, size_t ws_size,
                              hipStream_t stream) {
  (void)in_sizes; (void)n_in; (void)out_size; (void)ws_size;
  const float* x    = (const float*)d_in[0];
  const float* mems = (const float*)d_in[1];
  const float* u    = (const float*)d_in[2];
  const float* v    = (const float*)d_in[3];
  const float* Wqkv = (const float*)d_in[4];
  const float* Wo   = (const float*)d_in[5];
  const float* Wr   = (const float*)d_in[6];
  const float* ln1g = (const float*)d_in[7];
  const float* ln1b = (const float*)d_in[8];
  const float* W1   = (const float*)d_in[9];
  const float* b1   = (const float*)d_in[10];
  const float* W2   = (const float*)d_in[11];
  const float* b2   = (const float*)d_in[12];
  const float* ln2g = (const float*)d_in[13];
  const float* ln2b = (const float*)d_in[14];

  // ---- workspace carve-up (~105 MB total) ----
  size_t off = 0;
  char* ws = (char*)d_ws;
  auto alloc = [&](size_t bytes) { size_t o = off; off += (bytes + 255) & ~(size_t)255; return o; };
  __bf16* wT    = (__bf16*)(ws + alloc((size_t)DINNER * DMODEL * 2));        // 8.4 MB reused per GEMM
  char*   R1    = (char*)(ws + alloc((size_t)(KLEN_ * BS) * THD * 2));       // 25.2 MB: heads | proj+ff1
  __bf16* heads = (__bf16*)R1;
  float*  proj  = (float*)R1;                                                // 8 MB (after heads dead)
  __bf16* ff1   = (__bf16*)(R1 + (size_t)ROWS_H * DMODEL * 4);               // 16 MB
  __bf16* av    = (__bf16*)(ws + alloc((size_t)ROWS_H * HD_ * 2));           // 4.2 MB (aliased: memsb)
  __bf16* memsb = av;  // bf16 cast of mems[i]; dead before av is written
  __bf16* r_bf  = (__bf16*)(ws + alloc((size_t)KLEN_ * DMODEL * 2));         // 2 MB
  __bf16* rk    = (__bf16*)(ws + alloc((size_t)KLEN_ * HD_ * 2));            // 2 MB
  __bf16* qu    = (__bf16*)(ws + alloc((size_t)BS * NH * QL * DHEAD * 2));   // 4.2 MB
  __bf16* qv    = (__bf16*)(ws + alloc((size_t)BS * NH * QL * DHEAD * 2));   // 4.2 MB
  __bf16* vt    = (__bf16*)(ws + alloc((size_t)BS * NH * DHEAD * KLEN_ * 2));// 8.4 MB
  float*  score = (float*)(ws + alloc((size_t)NH * QL * KLEN_ * 4));         // 33.5 MB (one batch-chunk)
  float*  hm    = (float*)(ws + alloc((size_t)ROWS_H * DMODEL * 4));         // 8.4 MB
  __bf16* hbf   = (__bf16*)(ws + alloc((size_t)ROWS_H * DMODEL * 2));        // 4.2 MB

  const long QK  = (long)QL * KLEN_;       // 524288
  const long AQK = (long)QL * (2 * KLEN_); // attn (bf16, stride 2*KLEN_) per-head size

  posemb_kernel<<<(KLEN_ * DMODEL) / 256, 256, 0, stream>>>(r_bf);
  init_h<<<(ROWS_H * DMODEL) / 256, 256, 0, stream>>>(x, hm, hbf, ROWS_H * DMODEL);

  for (int i = 0; i < NL; ++i) {
    // ---- QKV: rows [0,2048) from mems[i] (cast to bf16), rows [2048,4096) from h ----
    cast_f32_bf16<<<(MLEN * BS * DMODEL) / 256, 256, 0, stream>>>(
        mems + (size_t)i * MLEN * BS * DMODEL, memsb, MLEN * BS * DMODEL);
    transpose_f32_bf16<<<dim3(THD / 64, DMODEL / 64), dim3(32, 8), 0, stream>>>(
        Wqkv + (size_t)i * DMODEL * THD, (unsigned short*)wT, DMODEL, THD);
    gemm_bt<128, 128, 4, 4, EPI_BF16><<<dim3(16, 24, 1), 256, 0, stream>>>(
        memsb, wT, heads, nullptr, DMODEL, DMODEL, DMODEL, THD, 0, 0, 0);
    gemm_bt<128, 128, 4, 4, EPI_BF16><<<dim3(16, 24, 1), 256, 0, stream>>>(
        hbf, wT, heads + (size_t)ROWS_H * THD, nullptr,
        DMODEL, DMODEL, DMODEL, THD, 0, 0, 0);
    // ---- rk = r @ W_r ----
    transpose_f32_bf16<<<dim3(HD_ / 64, DMODEL / 64), dim3(32, 8), 0, stream>>>(
        Wr + (size_t)i * DMODEL * HD_, (unsigned short*)wT, DMODEL, HD_);
    gemm_bt<128, 128, 4, 4, EPI_BF16><<<dim3(8, 8, 1), 256, 0, stream>>>(
        r_bf, wT, rk, nullptr, DMODEL, DMODEL, DMODEL, HD_, 0, 0, 0);

    build_quqv<<<(BS * NH * QL * DHEAD) / 256, 256, 0, stream>>>(heads, u, v, qu, qv);
    build_vt<<<dim3(KLEN_ / 64, BS * NH), dim3(64, 4), 0, stream>>>(
        (const unsigned short*)heads, (unsigned short*)vt);

    // ---- attention, chunked by batch b (16 heads per chunk) ----
    for (int b = 0; b < BS; ++b) {
      // AC: per n: (512x64)@(64x1024) -> score fp32
      gemm_bt<128, 128, 4, 4, EPI_F32><<<dim3(4, 8, 16), 256, 0, stream>>>(
          qu + (size_t)b * NH * QL * DHEAD, heads + HD_ + (size_t)b * THD, score, nullptr,
          DHEAD, DHEAD, BS * THD, KLEN_,
          (long)QL * DHEAD, 64L, QK);
      // BD: per n: (512x64)@(64x1024) with rel-shift scatter-add into score
      gemm_bt<128, 128, 4, 4, EPI_SHIFT><<<dim3(4, 8, 16), 256, 0, stream>>>(
          qv + (size_t)b * NH * QL * DHEAD, rk, score, nullptr,
          DHEAD, DHEAD, HD_, KLEN_,
          (long)QL * DHEAD, 64L, QK);
      softmax_kernel<<<NH * QL, 256, 0, stream>>>(score);
      // AV: per n: (512x1024)@(1024x64); attn = bf16 in-place in score rows (lda 2*KLEN_)
      gemm_bt<128, 64, 4, 2, EPI_BF16><<<dim3(4, 1, 16), 256, 0, stream>>>(
          (const __bf16*)score, vt + (size_t)b * NH * DHEAD * KLEN_,
          av + (size_t)b * HD_, nullptr,
          KLEN_, 2 * KLEN_, KLEN_, BS * HD_,
          AQK, (long)DHEAD * KLEN_, (long)DHEAD);
    }

    // ---- O-proj -> proj fp32 (aliases heads; heads dead now) ----
    transpose_f32_bf16<<<dim3(DMODEL / 64, HD_ / 64), dim3(32, 8), 0, stream>>>(
        Wo + (size_t)i * HD_ * DMODEL, (unsigned short*)wT, HD_, DMODEL);
    gemm_bt<128, 128, 4, 4, EPI_BIAS_F32><<<dim3(16, 8, 1), 256, 0, stream>>>(
        av, wT, proj, nullptr, HD_, HD_, HD_, DMODEL, 0, 0, 0);
    ln_kernel<<<ROWS_H, 256, 0, stream>>>(hm, proj, ln1g + i * DMODEL, ln1b + i * DMODEL,
                                          hbf, nullptr);

    // ---- FF1 ----
    transpose_f32_bf16<<<dim3(DINNER / 64, DMODEL / 64), dim3(32, 8), 0, stream>>>(
        W1 + (size_t)i * DMODEL * DINNER, (unsigned short*)wT, DMODEL, DINNER);
    gemm_bt<128, 128, 4, 4, EPI_RELU_BF16><<<dim3(16, 32, 1), 256, 0, stream>>>(
        hbf, wT, ff1, b1 + i * DINNER, DMODEL, DMODEL, DMODEL, DINNER, 0, 0, 0);
    // ---- FF2 ----
    transpose_f32_bf16<<<dim3(DMODEL / 64, DINNER / 64), dim3(32, 8), 0, stream>>>(
        W2 + (size_t)i * DINNER * DMODEL, (unsigned short*)wT, DINNER, DMODEL);
    gemm_bt<128, 128, 4, 4, EPI_BIAS_F32><<<dim3(16, 8, 1), 256, 0, stream>>>(
        ff1, wT, proj, b2 + i * DMODEL, DINNER, DINNER, DINNER, DMODEL, 0, 0, 0);
    ln_kernel<<<ROWS_H, 256, 0, stream>>>(hm, proj, ln2g + i * DMODEL, ln2b + i * DMODEL,
                                          hbf, (i == NL - 1) ? (float*)d_out : nullptr);
  }
}

// Round 5
// 1685.656 us; speedup vs baseline: 1.4846x; 1.4846x over previous
//
#include <hip/hip_runtime.h>
#include <hip/hip_bf16.h>
#include <cstdint>

// Problem dims (Transformer-XL)
#define QL      512
#define BS      4
#define DMODEL  1024
#define NL      4
#define NH      16
#define DHEAD   64
#define DINNER  4096
#define MLEN    512
#define KLEN_   1024   // MLEN + QL
#define HD_     1024   // NH*DHEAD
#define THD     3072   // 3*HD
#define ROWS_H   2048  // QL*BS

typedef __attribute__((ext_vector_type(8))) __bf16 bf16x8;
typedef __attribute__((ext_vector_type(4))) float  f32x4;

enum EpiMode { EPI_F32 = 0, EPI_BF16 = 1, EPI_RELU_BF16 = 2, EPI_BIAS_F32 = 3 };

// ======================= MFMA GEMM: C = A(MxK) * Bt(NxK)^T =======================
template<int BM, int BN, int WMT, int WNT, int EPI>
__global__ __launch_bounds__(256) void gemm_bt(
    const __bf16* __restrict__ A, const __bf16* __restrict__ Bt,
    void* __restrict__ Cv, const float* __restrict__ bias,
    int K, int lda, int ldb, int ldc,
    long sA, long Bn, long Cn)
{
  constexpr int WCOLS = BN / (WNT * 16);
  constexpr int WROWS = BM / (WMT * 16);
  static_assert(WCOLS * WROWS == 4, "must be 4 waves");
  constexpr int CHA = BM * 16 + 16;
  constexpr int CHB = BN * 16 + 16;
  __shared__ __align__(16) char smem[4 * CHA + 4 * CHB];
  char* sAm = smem;
  char* sBm = smem + 4 * CHA;

  const int bz = blockIdx.z;
  A  += (size_t)bz * sA;
  Bt += (size_t)bz * Bn;
  const size_t coff = (size_t)bz * Cn;

  const int tid  = threadIdx.x;
  const int wave = tid >> 6, lane = tid & 63;
  const int quad = lane >> 4, mrow = lane & 15;
  const int wr = wave / WCOLS, wc = wave % WCOLS;
  const int bm0 = blockIdx.x * BM, bn0 = blockIdx.y * BN;

  const f32x4 zero = {0.f, 0.f, 0.f, 0.f};
  f32x4 acc[WMT][WNT];
#pragma unroll
  for (int a = 0; a < WMT; ++a)
#pragma unroll
    for (int b = 0; b < WNT; ++b) acc[a][b] = zero;

  for (int k0 = 0; k0 < K; k0 += 32) {
#pragma unroll
    for (int p = 0; p < BM / 64; ++p) {
      int idx = p * 256 + tid;
      int r = idx >> 2, q = idx & 3;
      bf16x8 va = *(const bf16x8*)(A + (size_t)(bm0 + r) * lda + k0 + q * 8);
      *(bf16x8*)(sAm + q * CHA + r * 16) = va;
    }
#pragma unroll
    for (int p = 0; p < BN / 64; ++p) {
      int idx = p * 256 + tid;
      int r = idx >> 2, q = idx & 3;
      bf16x8 vb = *(const bf16x8*)(Bt + (size_t)(bn0 + r) * ldb + k0 + q * 8);
      *(bf16x8*)(sBm + q * CHB + r * 16) = vb;
    }
    __syncthreads();
    bf16x8 afr[WMT], bfr[WNT];
#pragma unroll
    for (int mt = 0; mt < WMT; ++mt)
      afr[mt] = *(const bf16x8*)(sAm + quad * CHA + (wr * (WMT * 16) + mt * 16 + mrow) * 16);
#pragma unroll
    for (int nt = 0; nt < WNT; ++nt)
      bfr[nt] = *(const bf16x8*)(sBm + quad * CHB + (wc * (WNT * 16) + nt * 16 + mrow) * 16);
#pragma unroll
    for (int mt = 0; mt < WMT; ++mt)
#pragma unroll
      for (int nt = 0; nt < WNT; ++nt)
        acc[mt][nt] = __builtin_amdgcn_mfma_f32_16x16x32_bf16(afr[mt], bfr[nt], acc[mt][nt], 0, 0, 0);
    __syncthreads();
  }

#pragma unroll
  for (int mt = 0; mt < WMT; ++mt) {
#pragma unroll
    for (int nt = 0; nt < WNT; ++nt) {
#pragma unroll
      for (int rr = 0; rr < 4; ++rr) {
        int gm = bm0 + wr * (WMT * 16) + mt * 16 + quad * 4 + rr;
        int gn = bn0 + wc * (WNT * 16) + nt * 16 + mrow;
        float val = acc[mt][nt][rr];
        if constexpr (EPI == EPI_F32) {
          ((float*)Cv)[coff + (size_t)gm * ldc + gn] = val;
        } else if constexpr (EPI == EPI_BF16) {
          ((__bf16*)Cv)[coff + (size_t)gm * ldc + gn] = (__bf16)val;
        } else if constexpr (EPI == EPI_RELU_BF16) {
          val += bias[gn];
          ((__bf16*)Cv)[coff + (size_t)gm * ldc + gn] = (__bf16)fmaxf(val, 0.f);
        } else { // EPI_BIAS_F32
          if (bias) val += bias[gn];
          ((float*)Cv)[coff + (size_t)gm * ldc + gn] = val;
        }
      }
    }
  }
}

// ======================= fused flash attention with rel-shift =======================
// Block: 4 waves, 64 q-rows (i0 = blockIdx.x*64), one head bn = blockIdx.y (b=bn>>4,n=bn&15).
// Online softmax over 64-wide K-tiles. BD term handled via a rolling 2x64-chunk window
// of raw[i][c] = qv_i . rk_c in LDS (c = j-i+511; c_min per tile = j0-i0+448, 64-aligned).
__global__ __launch_bounds__(256) void flash_attn(
    const __bf16* __restrict__ qu,   // [bn][QL][64]
    const __bf16* __restrict__ qv,   // [bn][QL][64]
    const __bf16* __restrict__ heads,// [(j*BS+b)*THD + HD_ + n*64 + d] (K part)
    const __bf16* __restrict__ rk,   // [c][n*64+d], ld = HD_
    const __bf16* __restrict__ vt,   // [bn][64][KLEN_]  (V^T)
    __bf16* __restrict__ av)         // [(i*BS+b)*HD_ + n*64 + d]
{
  __shared__ __align__(16) char kh_t[64 * 144];   // K tile  [j][d], row stride 144 B
  __shared__ __align__(16) char rv_t[64 * 144];   // rk chunk [c][d], then V^T tile [d][j]
  __shared__ __align__(16) char p_t [64 * 144];   // P tile  [i][j] bf16
  __shared__ float raw[64 * 132];                 // raw[i_local][ring 128 cols], pad to 132

  const int t   = blockIdx.x;        // i-tile index 0..7
  const int i0  = t * 64;
  const int bn  = blockIdx.y;
  const int b   = bn >> 4, n = bn & 15;
  const int tid = threadIdx.x;
  const int wave = tid >> 6, lane = tid & 63;
  const int quad = lane >> 4, mrow = lane & 15;
  const f32x4 zero = {0.f, 0.f, 0.f, 0.f};

  // ---- Q fragments (A-operand, k-chunks 0-31 / 32-63) ----
  const __bf16* qub = qu + (size_t)bn * QL * DHEAD;
  const __bf16* qvb = qv + (size_t)bn * QL * DHEAD;
  const int qrow = i0 + wave * 16 + mrow;
  bf16x8 quf0 = *(const bf16x8*)(qub + (size_t)qrow * 64 + quad * 8);
  bf16x8 quf1 = *(const bf16x8*)(qub + (size_t)qrow * 64 + 32 + quad * 8);
  bf16x8 qvf0 = *(const bf16x8*)(qvb + (size_t)qrow * 64 + quad * 8);
  bf16x8 qvf1 = *(const bf16x8*)(qvb + (size_t)qrow * 64 + 32 + quad * 8);

  f32x4 o[4];                       // O accum: 4 d-tiles x (4 rows rr)
#pragma unroll
  for (int dt = 0; dt < 4; ++dt) o[dt] = zero;
  float m_r[4], l_r[4];
#pragma unroll
  for (int rr = 0; rr < 4; ++rr) { m_r[rr] = -3.0e38f; l_r[rr] = 0.f; }

  // staging coords: 64x64 bf16 tile = 2 passes of (32 rows x 64 elems)
  const int sr = tid >> 3;          // 0..31
  const int sc = (tid & 7) * 8;     // 0..56

  // ---- pre-loop: raw chunk c0 = 448 - i0 (64-aligned, in [0,448]) ----
  const int c0 = 448 - i0;
#pragma unroll
  for (int p = 0; p < 2; ++p) {
    int r = p * 32 + sr;
    bf16x8 vv = *(const bf16x8*)(rk + (size_t)(c0 + r) * HD_ + n * 64 + sc);
    *(bf16x8*)(rv_t + r * 144 + sc * 2) = vv;
  }
  __syncthreads();
  {
    int slot = ((c0 >> 6) & 1) * 64;
#pragma unroll
    for (int ct = 0; ct < 4; ++ct) {
      bf16x8 b0 = *(const bf16x8*)(rv_t + (ct * 16 + mrow) * 144 + quad * 16);
      bf16x8 b1 = *(const bf16x8*)(rv_t + (ct * 16 + mrow) * 144 + 64 + quad * 16);
      f32x4 r = __builtin_amdgcn_mfma_f32_16x16x32_bf16(qvf0, b0, zero, 0, 0, 0);
      r = __builtin_amdgcn_mfma_f32_16x16x32_bf16(qvf1, b1, r, 0, 0, 0);
#pragma unroll
      for (int rr = 0; rr < 4; ++rr)
        raw[(wave * 16 + quad * 4 + rr) * 132 + slot + ct * 16 + mrow] = r[rr];
    }
  }
  __syncthreads();

  const int i_base = i0 + wave * 16 + quad * 4;
  const int nt = t + 9;             // K-tiles: j0 up to 64*(t+8)
  for (int k = 0; k < nt; ++k) {
    const int j0 = k * 64;
    // (a) stage K tile + next rk chunk
#pragma unroll
    for (int p = 0; p < 2; ++p) {
      int r = p * 32 + sr;
      bf16x8 kv = *(const bf16x8*)(heads + (size_t)((j0 + r) * BS + b) * THD + HD_ + n * 64 + sc);
      *(bf16x8*)(kh_t + r * 144 + sc * 2) = kv;
    }
    const int c0n = c0 + 64 * (k + 1);
    if (c0n < KLEN_) {
#pragma unroll
      for (int p = 0; p < 2; ++p) {
        int r = p * 32 + sr;
        bf16x8 rv = *(const bf16x8*)(rk + (size_t)(c0n + r) * HD_ + n * 64 + sc);
        *(bf16x8*)(rv_t + r * 144 + sc * 2) = rv;
      }
    }
    __syncthreads();
    // (c) raw MFMA for new chunk
    if (c0n < KLEN_) {
      int slot = ((c0n >> 6) & 1) * 64;
#pragma unroll
      for (int ct = 0; ct < 4; ++ct) {
        bf16x8 b0 = *(const bf16x8*)(rv_t + (ct * 16 + mrow) * 144 + quad * 16);
        bf16x8 b1 = *(const bf16x8*)(rv_t + (ct * 16 + mrow) * 144 + 64 + quad * 16);
        f32x4 r = __builtin_amdgcn_mfma_f32_16x16x32_bf16(qvf0, b0, zero, 0, 0, 0);
        r = __builtin_amdgcn_mfma_f32_16x16x32_bf16(qvf1, b1, r, 0, 0, 0);
#pragma unroll
        for (int rr = 0; rr < 4; ++rr)
          raw[(wave * 16 + quad * 4 + rr) * 132 + slot + ct * 16 + mrow] = r[rr];
      }
    }
    // AC MFMA from kh_t
    f32x4 s[4];
#pragma unroll
    for (int ct = 0; ct < 4; ++ct) {
      bf16x8 b0 = *(const bf16x8*)(kh_t + (ct * 16 + mrow) * 144 + quad * 16);
      bf16x8 b1 = *(const bf16x8*)(kh_t + (ct * 16 + mrow) * 144 + 64 + quad * 16);
      s[ct] = __builtin_amdgcn_mfma_f32_16x16x32_bf16(quf0, b0, zero, 0, 0, 0);
      s[ct] = __builtin_amdgcn_mfma_f32_16x16x32_bf16(quf1, b1, s[ct], 0, 0, 0);
    }
    __syncthreads();   // raw writes visible; rv_t free for V^T
    // stage V^T tile into rv_t
#pragma unroll
    for (int p = 0; p < 2; ++p) {
      int r = p * 32 + sr;
      bf16x8 vv = *(const bf16x8*)(vt + (size_t)bn * (DHEAD * KLEN_) + (size_t)r * KLEN_ + j0 + sc);
      *(bf16x8*)(rv_t + r * 144 + sc * 2) = vv;
    }
    // (e) rel-shift add + mask + online softmax
#pragma unroll
    for (int ct = 0; ct < 4; ++ct) {
#pragma unroll
      for (int rr = 0; rr < 4; ++rr) {
        int i = i_base + rr;
        int j = j0 + ct * 16 + mrow;
        float val;
        if (j - i <= MLEN) {
          int c = j - i + (QL - 1);
          int col = ((c >> 6) & 1) * 64 + (c & 63);
          val = (s[ct][rr] + raw[(wave * 16 + quad * 4 + rr) * 132 + col]) * 0.125f;
        } else val = -3.0e38f;
        s[ct][rr] = val;
      }
    }
    float alpha[4];
#pragma unroll
    for (int rr = 0; rr < 4; ++rr) {
      float mx = fmaxf(fmaxf(s[0][rr], s[1][rr]), fmaxf(s[2][rr], s[3][rr]));
#pragma unroll
      for (int off = 1; off < 16; off <<= 1) mx = fmaxf(mx, __shfl_xor(mx, off));
      float m_new = fmaxf(m_r[rr], mx);
      alpha[rr] = __expf(m_r[rr] - m_new);
      m_r[rr] = m_new;
      float rs = 0.f;
#pragma unroll
      for (int ct = 0; ct < 4; ++ct) {
        float pv = __expf(s[ct][rr] - m_new);
        s[ct][rr] = pv;
        rs += pv;
      }
#pragma unroll
      for (int off = 1; off < 16; off <<= 1) rs += __shfl_xor(rs, off);
      l_r[rr] = l_r[rr] * alpha[rr] + rs;
    }
#pragma unroll
    for (int dt = 0; dt < 4; ++dt)
#pragma unroll
      for (int rr = 0; rr < 4; ++rr) o[dt][rr] *= alpha[rr];
    // write P (bf16) to p_t
#pragma unroll
    for (int ct = 0; ct < 4; ++ct)
#pragma unroll
      for (int rr = 0; rr < 4; ++rr)
        ((__bf16*)p_t)[(wave * 16 + quad * 4 + rr) * 72 + ct * 16 + mrow] = (__bf16)s[ct][rr];
    __syncthreads();   // V^T staged + P visible
    // (f) PV MFMA
    {
      bf16x8 pf0 = *(const bf16x8*)(p_t + (wave * 16 + mrow) * 144 + quad * 16);
      bf16x8 pf1 = *(const bf16x8*)(p_t + (wave * 16 + mrow) * 144 + 64 + quad * 16);
#pragma unroll
      for (int dt = 0; dt < 4; ++dt) {
        bf16x8 vf0 = *(const bf16x8*)(rv_t + (dt * 16 + mrow) * 144 + quad * 16);
        bf16x8 vf1 = *(const bf16x8*)(rv_t + (dt * 16 + mrow) * 144 + 64 + quad * 16);
        o[dt] = __builtin_amdgcn_mfma_f32_16x16x32_bf16(pf0, vf0, o[dt], 0, 0, 0);
        o[dt] = __builtin_amdgcn_mfma_f32_16x16x32_bf16(pf1, vf1, o[dt], 0, 0, 0);
      }
    }
    __syncthreads();   // before next-iter staging overwrites tiles
  }

  // epilogue: O / l -> av
#pragma unroll
  for (int dt = 0; dt < 4; ++dt) {
#pragma unroll
    for (int rr = 0; rr < 4; ++rr) {
      int i = i_base + rr;
      float outv = o[dt][rr] / l_r[rr];
      av[((size_t)i * BS + b) * HD_ + n * 64 + dt * 16 + mrow] = (__bf16)outv;
    }
  }
}

// ======================= helpers =======================

__global__ __launch_bounds__(256) void transpose_f32_bf16(
    const float* __restrict__ in, unsigned short* __restrict__ out, int R, int C)
{
  __shared__ float tile[64][66];
  int c0 = blockIdx.x * 64, r0 = blockIdx.y * 64;
  int tx = threadIdx.x, ty = threadIdx.y;  // (32,8)
#pragma unroll
  for (int s = 0; s < 8; ++s) {
    int r = ty + s * 8;
    const float* p = in + (size_t)(r0 + r) * C + c0 + 2 * tx;
    tile[r][2 * tx]     = p[0];
    tile[r][2 * tx + 1] = p[1];
  }
  __syncthreads();
#pragma unroll
  for (int s = 0; s < 8; ++s) {
    int c = ty + s * 8;
    __bf16 lo = (__bf16)tile[2 * tx][c];
    __bf16 hi = (__bf16)tile[2 * tx + 1][c];
    unsigned int w = (unsigned int)*(unsigned short*)&lo |
                     ((unsigned int)*(unsigned short*)&hi << 16);
    *(unsigned int*)(out + (size_t)(c0 + c) * R + r0 + 2 * tx) = w;
  }
}

__global__ __launch_bounds__(256) void cast_f32_bf16(const float* __restrict__ in,
                                                     __bf16* __restrict__ out, int n)
{
  int i = blockIdx.x * 256 + threadIdx.x;
  if (i < n) out[i] = (__bf16)in[i];
}

__global__ __launch_bounds__(256) void posemb_kernel(__bf16* __restrict__ r)
{
  int idx = blockIdx.x * 256 + threadIdx.x;        // KLEN_*DMODEL total
  int p = idx >> 10, c = idx & 1023;
  int t = c & 511;
  float invf = __expf(-((float)t / 512.0f) * 9.210340371976184f); // 10000^(-2t/D)
  float ang = (float)(KLEN_ - 1 - p) * invf;
  float val = (c < 512) ? sinf(ang) : cosf(ang);
  r[idx] = (__bf16)val;
}

__global__ __launch_bounds__(256) void init_h(const float* __restrict__ x,
                                              float* __restrict__ hm,
                                              __bf16* __restrict__ hbf, int n)
{
  int i = blockIdx.x * 256 + threadIdx.x;
  if (i < n) { float t = x[i]; hm[i] = t; hbf[i] = (__bf16)t; }
}

__global__ __launch_bounds__(256) void build_quqv(const __bf16* __restrict__ heads,
                                                  const float* __restrict__ u,
                                                  const float* __restrict__ v,
                                                  __bf16* __restrict__ qu,
                                                  __bf16* __restrict__ qv)
{
  int idx = blockIdx.x * 256 + threadIdx.x;   // BS*NH*QL*DHEAD total
  int d = idx & 63;
  int i = (idx >> 6) & (QL - 1);
  int bn = idx >> 15;
  int b = bn >> 4, n = bn & 15;
  float q = (float)heads[(size_t)((MLEN + i) * BS + b) * THD + n * 64 + d];
  int ud = n * 64 + d;
  qu[idx] = (__bf16)(q + u[ud]);
  qv[idx] = (__bf16)(q + v[ud]);
}

__global__ __launch_bounds__(256) void build_vt(const unsigned short* __restrict__ heads,
                                                unsigned short* __restrict__ vt)
{
  __shared__ unsigned short tile[64][65];
  int bn = blockIdx.y; int b = bn >> 4, n = bn & 15;
  int j0 = blockIdx.x * 64;
  int tx = threadIdx.x, ty = threadIdx.y;  // (64,4)
#pragma unroll
  for (int s = 0; s < 16; ++s) {
    int j = ty + s * 4;
    tile[j][tx] = heads[(size_t)((j0 + j) * BS + b) * THD + 2048 + n * 64 + tx];
  }
  __syncthreads();
#pragma unroll
  for (int s = 0; s < 16; ++s) {
    int d = ty + s * 4;
    vt[(size_t)bn * DHEAD * KLEN_ + (size_t)d * KLEN_ + j0 + tx] = tile[tx][d];
  }
}

__global__ __launch_bounds__(256) void ln_kernel(float* __restrict__ hm,
                                                 const float* __restrict__ delta,
                                                 const float* __restrict__ g,
                                                 const float* __restrict__ b,
                                                 __bf16* __restrict__ hbf,
                                                 float* __restrict__ outf)
{
  int row = blockIdx.x;
  size_t base = (size_t)row * DMODEL;
  int tid = threadIdx.x;
  float x[4]; float sum = 0.f, sq = 0.f;
#pragma unroll
  for (int p = 0; p < 4; ++p) {
    int c = p * 256 + tid;
    float t = hm[base + c] + delta[base + c];
    x[p] = t; sum += t; sq += t * t;
  }
#pragma unroll
  for (int off = 32; off > 0; off >>= 1) { sum += __shfl_xor(sum, off); sq += __shfl_xor(sq, off); }
  __shared__ float rs[4], rq[4];
  int wave = tid >> 6, lane = tid & 63;
  if (lane == 0) { rs[wave] = sum; rq[wave] = sq; }
  __syncthreads();
  sum = rs[0] + rs[1] + rs[2] + rs[3];
  sq  = rq[0] + rq[1] + rq[2] + rq[3];
  float mu  = sum * (1.0f / DMODEL);
  float var = sq * (1.0f / DMODEL) - mu * mu;
  float rstd = rsqrtf(var + 1e-5f);
#pragma unroll
  for (int p = 0; p < 4; ++p) {
    int c = p * 256 + tid;
    float y = (x[p] - mu) * rstd * g[c] + b[c];
    hm[base + c] = y;
    hbf[base + c] = (__bf16)y;
    if (outf) outf[base + c] = y;
  }
}

// ======================= host =======================
extern "C" void kernel_launch(void* const* d_in, const int* in_sizes, int n_in,
                              void* d_out, int out_size, void* d_ws, size_t ws_size,
                              hipStream_t stream) {
  (void)in_sizes; (void)n_in; (void)out_size; (void)ws_size;
  const float* x    = (const float*)d_in[0];
  const float* mems = (const float*)d_in[1];
  const float* u    = (const float*)d_in[2];
  const float* v    = (const float*)d_in[3];
  const float* Wqkv = (const float*)d_in[4];
  const float* Wo   = (const float*)d_in[5];
  const float* Wr   = (const float*)d_in[6];
  const float* ln1g = (const float*)d_in[7];
  const float* ln1b = (const float*)d_in[8];
  const float* W1   = (const float*)d_in[9];
  const float* b1   = (const float*)d_in[10];
  const float* W2   = (const float*)d_in[11];
  const float* b2   = (const float*)d_in[12];
  const float* ln2g = (const float*)d_in[13];
  const float* ln2b = (const float*)d_in[14];

  // ---- workspace carve-up (~72 MB total) ----
  size_t off = 0;
  char* ws = (char*)d_ws;
  auto alloc = [&](size_t bytes) { size_t o = off; off += (bytes + 255) & ~(size_t)255; return o; };
  __bf16* wT    = (__bf16*)(ws + alloc((size_t)DINNER * DMODEL * 2));        // 8.4 MB reused per GEMM
  char*   R1    = (char*)(ws + alloc((size_t)(KLEN_ * BS) * THD * 2));       // 25.2 MB: heads | proj+ff1
  __bf16* heads = (__bf16*)R1;
  float*  proj  = (float*)R1;                                                // 8 MB (after heads dead)
  __bf16* ff1   = (__bf16*)(R1 + (size_t)ROWS_H * DMODEL * 4);               // 16 MB
  __bf16* av    = (__bf16*)(ws + alloc((size_t)ROWS_H * HD_ * 2));           // 4.2 MB (aliased: memsb)
  __bf16* memsb = av;  // bf16 cast of mems[i]; dead before av is written
  __bf16* r_bf  = (__bf16*)(ws + alloc((size_t)KLEN_ * DMODEL * 2));         // 2 MB
  __bf16* rk    = (__bf16*)(ws + alloc((size_t)KLEN_ * HD_ * 2));            // 2 MB
  __bf16* qu    = (__bf16*)(ws + alloc((size_t)BS * NH * QL * DHEAD * 2));   // 4.2 MB
  __bf16* qv    = (__bf16*)(ws + alloc((size_t)BS * NH * QL * DHEAD * 2));   // 4.2 MB
  __bf16* vt    = (__bf16*)(ws + alloc((size_t)BS * NH * DHEAD * KLEN_ * 2));// 8.4 MB
  float*  hm    = (float*)(ws + alloc((size_t)ROWS_H * DMODEL * 4));         // 8.4 MB
  __bf16* hbf   = (__bf16*)(ws + alloc((size_t)ROWS_H * DMODEL * 2));        // 4.2 MB

  posemb_kernel<<<(KLEN_ * DMODEL) / 256, 256, 0, stream>>>(r_bf);
  init_h<<<(ROWS_H * DMODEL) / 256, 256, 0, stream>>>(x, hm, hbf, ROWS_H * DMODEL);

  for (int i = 0; i < NL; ++i) {
    // ---- QKV: rows [0,2048) from mems[i] (cast to bf16), rows [2048,4096) from h ----
    cast_f32_bf16<<<(MLEN * BS * DMODEL) / 256, 256, 0, stream>>>(
        mems + (size_t)i * MLEN * BS * DMODEL, memsb, MLEN * BS * DMODEL);
    transpose_f32_bf16<<<dim3(THD / 64, DMODEL / 64), dim3(32, 8), 0, stream>>>(
        Wqkv + (size_t)i * DMODEL * THD, (unsigned short*)wT, DMODEL, THD);
    gemm_bt<128, 128, 4, 4, EPI_BF16><<<dim3(16, 24, 1), 256, 0, stream>>>(
        memsb, wT, heads, nullptr, DMODEL, DMODEL, DMODEL, THD, 0, 0, 0);
    gemm_bt<128, 128, 4, 4, EPI_BF16><<<dim3(16, 24, 1), 256, 0, stream>>>(
        hbf, wT, heads + (size_t)ROWS_H * THD, nullptr,
        DMODEL, DMODEL, DMODEL, THD, 0, 0, 0);
    // ---- rk = r @ W_r ----
    transpose_f32_bf16<<<dim3(HD_ / 64, DMODEL / 64), dim3(32, 8), 0, stream>>>(
        Wr + (size_t)i * DMODEL * HD_, (unsigned short*)wT, DMODEL, HD_);
    gemm_bt<128, 128, 4, 4, EPI_BF16><<<dim3(8, 8, 1), 256, 0, stream>>>(
        r_bf, wT, rk, nullptr, DMODEL, DMODEL, DMODEL, HD_, 0, 0, 0);

    build_quqv<<<(BS * NH * QL * DHEAD) / 256, 256, 0, stream>>>(heads, u, v, qu, qv);
    build_vt<<<dim3(KLEN_ / 64, BS * NH), dim3(64, 4), 0, stream>>>(
        (const unsigned short*)heads, (unsigned short*)vt);

    // ---- fused attention (AC + rel-shift BD + softmax + PV) ----
    flash_attn<<<dim3(8, 64), 256, 0, stream>>>(qu, qv, heads, rk, vt, av);

    // ---- O-proj -> proj fp32 (aliases heads; heads dead now) ----
    transpose_f32_bf16<<<dim3(DMODEL / 64, HD_ / 64), dim3(32, 8), 0, stream>>>(
        Wo + (size_t)i * HD_ * DMODEL, (unsigned short*)wT, HD_, DMODEL);
    gemm_bt<128, 128, 4, 4, EPI_BIAS_F32><<<dim3(16, 8, 1), 256, 0, stream>>>(
        av, wT, proj, nullptr, HD_, HD_, HD_, DMODEL, 0, 0, 0);
    ln_kernel<<<ROWS_H, 256, 0, stream>>>(hm, proj, ln1g + i * DMODEL, ln1b + i * DMODEL,
                                          hbf, nullptr);

    // ---- FF1 ----
    transpose_f32_bf16<<<dim3(DINNER / 64, DMODEL / 64), dim3(32, 8), 0, stream>>>(
        W1 + (size_t)i * DMODEL * DINNER, (unsigned short*)wT, DMODEL, DINNER);
    gemm_bt<128, 128, 4, 4, EPI_RELU_BF16><<<dim3(16, 32, 1), 256, 0, stream>>>(
        hbf, wT, ff1, b1 + i * DINNER, DMODEL, DMODEL, DMODEL, DINNER, 0, 0, 0);
    // ---- FF2 ----
    transpose_f32_bf16<<<dim3(DMODEL / 64, DINNER / 64), dim3(32, 8), 0, stream>>>(
        W2 + (size_t)i * DINNER * DMODEL, (unsigned short*)wT, DINNER, DMODEL);
    gemm_bt<128, 128, 4, 4, EPI_BIAS_F32><<<dim3(16, 8, 1), 256, 0, stream>>>(
        ff1, wT, proj, b2 + i * DMODEL, DINNER, DINNER, DINNER, DMODEL, 0, 0, 0);
    ln_kernel<<<ROWS_H, 256, 0, stream>>>(hm, proj, ln2g + i * DMODEL, ln2b + i * DMODEL,
                                          hbf, (i == NL - 1) ? (float*)d_out : nullptr);
  }
}